// Round 1
// baseline (399.110 us; speedup 1.0000x reference)
//
#include <hip/hip_runtime.h>

typedef unsigned short u16;
typedef __bf16 v8bf __attribute__((ext_vector_type(8)));
typedef float f32x4 __attribute__((ext_vector_type(4)));

#define LOG2E 1.4426950408889634f
#define SCALE 0.10206207261596577f  // 96^-0.5

__device__ __forceinline__ u16 f2b(float x) {
  unsigned u = __builtin_bit_cast(unsigned, x);
  unsigned r = (u + 0x7FFFu + ((u >> 16) & 1u)) >> 16;  // RNE
  return (u16)r;
}

union V8U { uint4 u; u16 s[8]; };

// ---------------- prep kernels ----------------
__global__ __launch_bounds__(256) void k_cvt_x(const float* __restrict__ x, u16* __restrict__ xb, int n4) {
  int i = blockIdx.x * 256 + threadIdx.x;
  if (i >= n4) return;
  float4 v = ((const float4*)x)[i];
  ushort4 o;
  o.x = f2b(v.x); o.y = f2b(v.y); o.z = f2b(v.z); o.w = f2b(v.w);
  ((ushort4*)xb)[i] = o;
}

// wct[c][e] = w_m[h][e][d], c = m*768 + h*96 + d  (B^T layout for GEMM)
__global__ __launch_bounds__(256) void k_build_wct(const float* __restrict__ wq, const float* __restrict__ wk,
                                                   const float* __restrict__ wv, u16* __restrict__ wct) {
  int t = blockIdx.x * 256 + threadIdx.x;
  if (t >= 2304 * 96) return;
  int c = t / 96, e8 = t - (t / 96) * 96;
  int m = c / 768, rem = c - m * 768;
  int h = rem / 96, d = rem - (rem / 96) * 96;
  const float* src = (m == 0) ? wq : (m == 1) ? wk : wv;
  const float* p = src + (size_t)h * 73728 + d;
  V8U o;
  for (int i = 0; i < 8; ++i) o.s[i] = f2b(p[(size_t)(e8 * 8 + i) * 96]);
  *(uint4*)&wct[(size_t)c * 768 + e8 * 8] = o.u;
}

// wot[e][k] = w_o_flat[k*768 + e]  (B^T layout for out GEMM, k = h*96+d)
__global__ __launch_bounds__(256) void k_build_wot(const float* __restrict__ wo, u16* __restrict__ wot) {
  int t = blockIdx.x * 256 + threadIdx.x;
  if (t >= 768 * 96) return;
  int e = t / 96, k8 = t - (t / 96) * 96;
  V8U o;
  for (int i = 0; i < 8; ++i) o.s[i] = f2b(wo[(size_t)(k8 * 8 + i) * 768 + e]);
  *(uint4*)&wot[(size_t)e * 768 + k8 * 8] = o.u;
}

// emb[h][p] = sum_d rel_emb[h][p][d][0]
__global__ __launch_bounds__(256) void k_emb(const float* __restrict__ rel, float* __restrict__ emb) {
  int t = blockIdx.x * 256 + threadIdx.x;
  if (t >= 8 * 199) return;
  int h = t / 199, p = t - h * 199;
  const float4* src = (const float4*)(rel + (size_t)(h * 199 + p) * 96);
  float s = 0.f;
  for (int i = 0; i < 24; ++i) { float4 v = src[i]; s += v.x + v.y + v.z + v.w; }
  emb[h * 200 + p] = s;
}

// ---------------- 128x128 bf16 MFMA GEMM, K=768 ----------------
// A: [8192][768] bf16 row-major. Bm: [N][768] bf16 (row = output col, i.e. B^T).
// EPI 0: scatter-write Q/K/V bf16 (col -> m,h,d).  EPI 1: f32 write to C[row][col], N=768.
template <int EPI>
__global__ __launch_bounds__(256) void gemm128(const u16* __restrict__ A, const u16* __restrict__ Bm,
                                               void* __restrict__ Cout) {
  __shared__ alignas(16) u16 Al[128][72];
  __shared__ alignas(16) u16 Bl[128][72];
  const int tid = threadIdx.x;
  const int lane = tid & 63, wid = tid >> 6;
  const int g = lane >> 4, r16 = lane & 15;
  const int wr = wid >> 1, wc = wid & 1;
  const int Mbase = blockIdx.y * 128, Nbase = blockIdx.x * 128;
  f32x4 acc[4][4];
  for (int i = 0; i < 4; ++i)
    for (int j = 0; j < 4; ++j) acc[i][j] = (f32x4){0.f, 0.f, 0.f, 0.f};

  for (int kt = 0; kt < 12; ++kt) {
    for (int i = 0; i < 4; ++i) {
      int idx = tid + i * 256;
      int row = idx >> 3, c8 = idx & 7;
      *(uint4*)&Al[row][c8 * 8] = *(const uint4*)&A[(size_t)(Mbase + row) * 768 + kt * 64 + c8 * 8];
      *(uint4*)&Bl[row][c8 * 8] = *(const uint4*)&Bm[(size_t)(Nbase + row) * 768 + kt * 64 + c8 * 8];
    }
    __syncthreads();
    for (int ch = 0; ch < 2; ++ch) {
      v8bf af[4], bv[4];
      for (int mt = 0; mt < 4; ++mt) af[mt] = *(const v8bf*)&Al[64 * wr + 16 * mt + r16][ch * 32 + g * 8];
      for (int nt = 0; nt < 4; ++nt) bv[nt] = *(const v8bf*)&Bl[64 * wc + 16 * nt + r16][ch * 32 + g * 8];
      for (int mt = 0; mt < 4; ++mt)
        for (int nt = 0; nt < 4; ++nt)
          acc[mt][nt] = __builtin_amdgcn_mfma_f32_16x16x32_bf16(af[mt], bv[nt], acc[mt][nt], 0, 0, 0);
    }
    __syncthreads();
  }

  if (EPI == 0) {
    u16* qkv = (u16*)Cout;
    for (int mt = 0; mt < 4; ++mt)
      for (int nt = 0; nt < 4; ++nt) {
        int col = Nbase + 64 * wc + 16 * nt + r16;
        int m = col / 768, rem = col - m * 768;
        int h = rem / 96, d = rem - h * 96;
        for (int r = 0; r < 4; ++r) {
          int row = Mbase + 64 * wr + 16 * mt + 4 * g + r;
          int b = row >> 11, s = row & 2047;
          qkv[(size_t)m * 6291456 + ((size_t)(b * 8 + h) * 2048 + s) * 96 + d] = f2b(acc[mt][nt][r]);
        }
      }
  } else {
    float* C = (float*)Cout;
    for (int mt = 0; mt < 4; ++mt)
      for (int nt = 0; nt < 4; ++nt) {
        int col = Nbase + 64 * wc + 16 * nt + r16;
        for (int r = 0; r < 4; ++r) {
          int row = Mbase + 64 * wr + 16 * mt + 4 * g + r;
          C[(size_t)row * 768 + col] = acc[mt][nt][r];
        }
      }
  }
}

// ---------------- flash attention ----------------
// grid: x = 32 q-tiles (64 rows each), y = 32 (b*8+h). 256 threads, 4 waves x 16 q-rows.
__global__ __launch_bounds__(256) void attn(const u16* __restrict__ q_ws, const u16* __restrict__ k_ws,
                                            const u16* __restrict__ v_ws, const float* __restrict__ emb_ws,
                                            u16* __restrict__ ctx) {
  __shared__ alignas(16) u16 Kl[32][104];    // K tile row-major, +8 pad
  __shared__ alignas(16) u16 VTl[96][40];    // V tile transposed [d][k], +8 pad
  __shared__ alignas(16) u16 Pl[4][16][40];  // per-wave P buffer [q][k], +8 pad
  __shared__ float emb[200];
  const int tid = threadIdx.x;
  const int lane = tid & 63, wid = tid >> 6;
  const int g = lane >> 4, r16 = lane & 15;
  const int bh = blockIdx.y;
  const int h = bh & 7;
  const int q0 = blockIdx.x * 64;
  for (int i = tid; i < 199; i += 256) emb[i] = emb_ws[h * 200 + i];

  const int qrow = q0 + wid * 16 + r16;
  const u16* qptr = q_ws + ((size_t)bh * 2048 + qrow) * 96;
  v8bf qf[3];
  for (int c = 0; c < 3; ++c) qf[c] = *(const v8bf*)&qptr[c * 32 + g * 8];

  float m_run = -1e30f, l_run = 0.f;
  f32x4 acc[6];
  for (int nt = 0; nt < 6; ++nt) acc[nt] = (f32x4){0.f, 0.f, 0.f, 0.f};
  const u16* kbp = k_ws + (size_t)bh * 2048 * 96;
  const u16* vbp = v_ws + (size_t)bh * 2048 * 96;

  for (int kv = 0; kv < 64; ++kv) {
    const int kb = kv * 32;
    __syncthreads();  // previous-tile LDS reads done (also covers emb on iter 0)
    for (int i = tid; i < 384; i += 256) {
      int row = i / 12, c8 = i - (i / 12) * 12;
      *(uint4*)&Kl[row][c8 * 8] = *(const uint4*)(kbp + (size_t)(kb + row) * 96 + c8 * 8);
      V8U vv;
      vv.u = *(const uint4*)(vbp + (size_t)(kb + row) * 96 + c8 * 8);
      for (int ii = 0; ii < 8; ++ii) {  // staggered scatter to break bank conflicts
        int j = (ii + c8) & 7;
        VTl[c8 * 8 + j][row] = vv.s[j];
      }
    }
    __syncthreads();

    // swapped QK^T: D[m=kcol][n=qrow]; lane owns q-row r16, kcols {16mt+4g+r}
    f32x4 sa[2];
    sa[0] = (f32x4){0.f, 0.f, 0.f, 0.f};
    sa[1] = (f32x4){0.f, 0.f, 0.f, 0.f};
    for (int mt = 0; mt < 2; ++mt)
      for (int c = 0; c < 3; ++c) {
        v8bf kf = *(const v8bf*)&Kl[16 * mt + r16][c * 32 + g * 8];
        sa[mt] = __builtin_amdgcn_mfma_f32_16x16x32_bf16(kf, qf[c], sa[mt], 0, 0, 0);
      }

    float lg[2][4], pmax = -1e30f;
    for (int mt = 0; mt < 2; ++mt)
      for (int r = 0; r < 4; ++r) {
        int kpos = kb + 16 * mt + 4 * g + r;
        int rel = kpos - qrow;
        rel = min(99, max(-99, rel));
        float v = sa[mt][r] * SCALE + emb[rel + 99];
        lg[mt][r] = v;
        pmax = fmaxf(pmax, v);
      }
    pmax = fmaxf(pmax, __shfl_xor(pmax, 16));
    pmax = fmaxf(pmax, __shfl_xor(pmax, 32));
    float m_new = fmaxf(m_run, pmax);
    float corr = exp2f((m_run - m_new) * LOG2E);
    float psum = 0.f;
    u16 pb[2][4];
    for (int mt = 0; mt < 2; ++mt)
      for (int r = 0; r < 4; ++r) {
        float p = exp2f((lg[mt][r] - m_new) * LOG2E);
        psum += p;
        pb[mt][r] = f2b(p);
      }
    psum += __shfl_xor(psum, 16);
    psum += __shfl_xor(psum, 32);
    l_run = l_run * corr + psum;
    m_run = m_new;

    // P -> per-wave LDS (no barrier: wave-private buffer)
    for (int mt = 0; mt < 2; ++mt) {
      uint2 pv;
      pv.x = (unsigned)pb[mt][0] | ((unsigned)pb[mt][1] << 16);
      pv.y = (unsigned)pb[mt][2] | ((unsigned)pb[mt][3] << 16);
      *(uint2*)&Pl[wid][r16][16 * mt + 4 * g] = pv;
    }
    float corrD[4];
    for (int r = 0; r < 4; ++r) corrD[r] = __shfl(corr, 4 * g + r);
    v8bf pf = *(const v8bf*)&Pl[wid][r16][g * 8];
    for (int nt = 0; nt < 6; ++nt) {
      v8bf vf = *(const v8bf*)&VTl[16 * nt + r16][g * 8];
      f32x4 a = acc[nt];
      for (int r = 0; r < 4; ++r) a[r] *= corrD[r];
      acc[nt] = __builtin_amdgcn_mfma_f32_16x16x32_bf16(pf, vf, a, 0, 0, 0);
    }
  }

  float lD[4];
  for (int r = 0; r < 4; ++r) lD[r] = 1.f / __shfl(l_run, 4 * g + r);
  const int b = bh >> 3;
  for (int nt = 0; nt < 6; ++nt) {
    int col = h * 96 + 16 * nt + r16;
    for (int r = 0; r < 4; ++r) {
      int s = q0 + wid * 16 + 4 * g + r;
      ctx[((size_t)b * 2048 + s) * 768 + col] = f2b(acc[nt][r] * lD[r]);
    }
  }
}

// ---------------- launch ----------------
extern "C" void kernel_launch(void* const* d_in, const int* in_sizes, int n_in,
                              void* d_out, int out_size, void* d_ws, size_t ws_size,
                              hipStream_t stream) {
  const float* x = (const float*)d_in[0];
  const float* wq = (const float*)d_in[1];
  const float* wk = (const float*)d_in[2];
  const float* wv = (const float*)d_in[3];
  const float* wo = (const float*)d_in[4];
  const float* rel = (const float*)d_in[5];

  char* ws = (char*)d_ws;
  u16* xb = (u16*)(ws + 0);              // 12,582,912 B
  u16* wct = (u16*)(ws + 12582912);      //  3,538,944 B
  u16* wot = (u16*)(ws + 16121856);      //  1,179,648 B
  float* emb = (float*)(ws + 17301504);  //      6,400 B (padded)
  u16* qkv = (u16*)(ws + 17309696);      // 37,748,736 B (Q|K|V)
  u16* ctx = (u16*)(ws + 55058432);      // 12,582,912 B

  k_cvt_x<<<6144, 256, 0, stream>>>(x, xb, 1572864);
  k_build_wct<<<864, 256, 0, stream>>>(wq, wk, wv, wct);
  k_build_wot<<<288, 256, 0, stream>>>(wo, wot);
  k_emb<<<7, 256, 0, stream>>>(rel, emb);

  dim3 gq(18, 64);
  gemm128<0><<<gq, 256, 0, stream>>>(xb, wct, (void*)qkv);

  dim3 ga(32, 32);
  attn<<<ga, 256, 0, stream>>>(qkv, qkv + 6291456, qkv + 2 * 6291456, emb, ctx);

  dim3 go(6, 64);
  gemm128<1><<<go, 256, 0, stream>>>(ctx, wot, d_out);
}

// Round 2
// 367.609 us; speedup vs baseline: 1.0857x; 1.0857x over previous
//
#include <hip/hip_runtime.h>

typedef unsigned short u16;
typedef __bf16 v8bf __attribute__((ext_vector_type(8)));
typedef float f32x4 __attribute__((ext_vector_type(4)));

#define LOG2E 1.4426950408889634f

__device__ __forceinline__ u16 f2b(float x) {
  unsigned u = __builtin_bit_cast(unsigned, x);
  unsigned r = (u + 0x7FFFu + ((u >> 16) & 1u)) >> 16;  // RNE
  return (u16)r;
}

union V8U { uint4 u; u16 s[8]; };

// ---------------- prep kernels ----------------
__global__ __launch_bounds__(256) void k_cvt_x(const float* __restrict__ x, u16* __restrict__ xb, int n4) {
  int i = blockIdx.x * 256 + threadIdx.x;
  if (i >= n4) return;
  float4 v = ((const float4*)x)[i];
  ushort4 o;
  o.x = f2b(v.x); o.y = f2b(v.y); o.z = f2b(v.z); o.w = f2b(v.w);
  ((ushort4*)xb)[i] = o;
}

// wct[c][e] = w_m[h][e][d], c = m*768 + h*96 + d  (B^T layout for GEMM)
// W_q gets pre-scaled by d^-1/2 * log2(e) so QK^T logits land in log2 domain.
__global__ __launch_bounds__(256) void k_build_wct(const float* __restrict__ wq, const float* __restrict__ wk,
                                                   const float* __restrict__ wv, u16* __restrict__ wct) {
  int t = blockIdx.x * 256 + threadIdx.x;
  if (t >= 2304 * 96) return;
  int c = t / 96, e8 = t - (t / 96) * 96;
  int m = c / 768, rem = c - m * 768;
  int h = rem / 96, d = rem - (rem / 96) * 96;
  const float* src = (m == 0) ? wq : (m == 1) ? wk : wv;
  float sc = (m == 0) ? (0.10206207261596577f * 1.4426950408889634f) : 1.0f;
  const float* p = src + (size_t)h * 73728 + d;
  V8U o;
  for (int i = 0; i < 8; ++i) o.s[i] = f2b(p[(size_t)(e8 * 8 + i) * 96] * sc);
  *(uint4*)&wct[(size_t)c * 768 + e8 * 8] = o.u;
}

// wot[e][k] = w_o_flat[k*768 + e]  (B^T layout for out GEMM, k = h*96+d)
__global__ __launch_bounds__(256) void k_build_wot(const float* __restrict__ wo, u16* __restrict__ wot) {
  int t = blockIdx.x * 256 + threadIdx.x;
  if (t >= 768 * 96) return;
  int e = t / 96, k8 = t - (t / 96) * 96;
  V8U o;
  for (int i = 0; i < 8; ++i) o.s[i] = f2b(wo[(size_t)(k8 * 8 + i) * 768 + e]);
  *(uint4*)&wot[(size_t)e * 768 + k8 * 8] = o.u;
}

// emb[h][p] = LOG2E * sum_d rel_emb[h][p][d][0]
__global__ __launch_bounds__(256) void k_emb(const float* __restrict__ rel, float* __restrict__ emb) {
  int t = blockIdx.x * 256 + threadIdx.x;
  if (t >= 8 * 199) return;
  int h = t / 199, p = t - h * 199;
  const float4* src = (const float4*)(rel + (size_t)(h * 199 + p) * 96);
  float s = 0.f;
  for (int i = 0; i < 24; ++i) { float4 v = src[i]; s += v.x + v.y + v.z + v.w; }
  emb[h * 200 + p] = s * LOG2E;
}

// ---------------- 128x128 bf16 MFMA GEMM, K=768 ----------------
// EPI 0: scatter-write Q/K bf16 [bh][s][d]; V transposed [bh][d][s].  EPI 1: f32 C[row][col].
template <int EPI>
__global__ __launch_bounds__(256) void gemm128(const u16* __restrict__ A, const u16* __restrict__ Bm,
                                               void* __restrict__ Cout) {
  __shared__ alignas(16) u16 Al[128][72];
  __shared__ alignas(16) u16 Bl[128][72];
  const int tid = threadIdx.x;
  const int lane = tid & 63, wid = tid >> 6;
  const int g = lane >> 4, r16 = lane & 15;
  const int wr = wid >> 1, wc = wid & 1;
  const int Mbase = blockIdx.y * 128, Nbase = blockIdx.x * 128;
  f32x4 acc[4][4];
  for (int i = 0; i < 4; ++i)
    for (int j = 0; j < 4; ++j) acc[i][j] = (f32x4){0.f, 0.f, 0.f, 0.f};

  for (int kt = 0; kt < 12; ++kt) {
    for (int i = 0; i < 4; ++i) {
      int idx = tid + i * 256;
      int row = idx >> 3, c8 = idx & 7;
      *(uint4*)&Al[row][c8 * 8] = *(const uint4*)&A[(size_t)(Mbase + row) * 768 + kt * 64 + c8 * 8];
      *(uint4*)&Bl[row][c8 * 8] = *(const uint4*)&Bm[(size_t)(Nbase + row) * 768 + kt * 64 + c8 * 8];
    }
    __syncthreads();
    for (int ch = 0; ch < 2; ++ch) {
      v8bf af[4], bv[4];
      for (int mt = 0; mt < 4; ++mt) af[mt] = *(const v8bf*)&Al[64 * wr + 16 * mt + r16][ch * 32 + g * 8];
      for (int nt = 0; nt < 4; ++nt) bv[nt] = *(const v8bf*)&Bl[64 * wc + 16 * nt + r16][ch * 32 + g * 8];
      for (int mt = 0; mt < 4; ++mt)
        for (int nt = 0; nt < 4; ++nt)
          acc[mt][nt] = __builtin_amdgcn_mfma_f32_16x16x32_bf16(af[mt], bv[nt], acc[mt][nt], 0, 0, 0);
    }
    __syncthreads();
  }

  if (EPI == 0) {
    u16* qkv = (u16*)Cout;
    for (int mt = 0; mt < 4; ++mt)
      for (int nt = 0; nt < 4; ++nt) {
        int col = Nbase + 64 * wc + 16 * nt + r16;
        int m = col / 768, rem = col - m * 768;
        int h = rem / 96, d = rem - h * 96;
        for (int r = 0; r < 4; ++r) {
          int row = Mbase + 64 * wr + 16 * mt + 4 * g + r;
          int b = row >> 11, s = row & 2047;
          size_t off;
          if (m == 2)  // V stored transposed: [bh][d][s]
            off = (size_t)2 * 6291456 + ((size_t)(b * 8 + h) * 96 + d) * 2048 + s;
          else
            off = (size_t)m * 6291456 + ((size_t)(b * 8 + h) * 2048 + s) * 96 + d;
          qkv[off] = f2b(acc[mt][nt][r]);
        }
      }
  } else {
    float* C = (float*)Cout;
    for (int mt = 0; mt < 4; ++mt)
      for (int nt = 0; nt < 4; ++nt) {
        int col = Nbase + 64 * wc + 16 * nt + r16;
        for (int r = 0; r < 4; ++r) {
          int row = Mbase + 64 * wr + 16 * mt + 4 * g + r;
          C[(size_t)row * 768 + col] = acc[mt][nt][r];
        }
      }
  }
}

// ---------------- flash attention v2 ----------------
// grid: x = 16 q-tiles (128 rows), y = 32 (b*8+h). 256 threads, 4 waves x 32 q-rows, KVBLK=64.
__global__ __launch_bounds__(256, 2) void attn(const u16* __restrict__ q_ws, const u16* __restrict__ k_ws,
                                               const u16* __restrict__ vt_ws, const float* __restrict__ emb_ws,
                                               u16* __restrict__ ctx) {
  __shared__ alignas(16) u16 Kl[64][104];    // K tile row-major [k][e]
  __shared__ alignas(16) u16 VTl[96][72];    // V^T tile [d][k]
  __shared__ alignas(16) u16 Pl[4][32][72];  // per-wave P [q][k]
  __shared__ float embL[200];
  const int tid = threadIdx.x;
  const int lane = tid & 63, wid = tid >> 6;
  const int g = lane >> 4, r16 = lane & 15;
  const int bh = blockIdx.y;
  const int h = bh & 7;
  const int q0 = blockIdx.x * 128;
  for (int i = tid; i < 199; i += 256) embL[i] = emb_ws[h * 200 + i];

  int qrow[2];
  v8bf qf[2][3];
  for (int sub = 0; sub < 2; ++sub) {
    qrow[sub] = q0 + wid * 32 + sub * 16 + r16;
    const u16* qptr = q_ws + ((size_t)bh * 2048 + qrow[sub]) * 96;
    for (int c = 0; c < 3; ++c) qf[sub][c] = *(const v8bf*)&qptr[c * 32 + g * 8];
  }

  float m_run[2] = {-1e30f, -1e30f}, l_run[2] = {0.f, 0.f};
  f32x4 acc[6][2];
  for (int nt = 0; nt < 6; ++nt)
    for (int sub = 0; sub < 2; ++sub) acc[nt][sub] = (f32x4){0.f, 0.f, 0.f, 0.f};

  // staging slot setup: 3 K chunks + 3 V^T chunks per thread per iter
  const u16* kbp = k_ws + (size_t)bh * 2048 * 96;
  const u16* vtp = vt_ws + (size_t)bh * 96 * 2048;
  const u16* gK[3]; const u16* gV[3];
  u16* lK[3]; u16* lV[3];
#pragma unroll
  for (int j = 0; j < 3; ++j) {
    int i = tid + j * 256;           // 0..767
    int row = i / 12, c8 = i - (i / 12) * 12;
    gK[j] = kbp + (size_t)row * 96 + c8 * 8;
    lK[j] = &Kl[row][c8 * 8];
    int dd = i >> 3, c4 = i & 7;
    gV[j] = vtp + (size_t)dd * 2048 + c4 * 8;
    lV[j] = &VTl[dd][c4 * 8];
  }
  uint4 rK[3], rV[3];
#pragma unroll
  for (int j = 0; j < 3; ++j) {  // prefetch tile 0
    rK[j] = *(const uint4*)gK[j]; gK[j] += 64 * 96;
    rV[j] = *(const uint4*)gV[j]; gV[j] += 64;
  }

  for (int kv = 0; kv < 32; ++kv) {
    const int kb = kv * 64;
    __syncthreads();  // previous compute done with LDS
#pragma unroll
    for (int j = 0; j < 3; ++j) {
      *(uint4*)lK[j] = rK[j];
      *(uint4*)lV[j] = rV[j];
    }
    if (kv != 31) {  // async prefetch next tile into regs; latency hides under compute
#pragma unroll
      for (int j = 0; j < 3; ++j) {
        rK[j] = *(const uint4*)gK[j]; gK[j] += 64 * 96;
        rV[j] = *(const uint4*)gV[j]; gV[j] += 64;
      }
    }
    __syncthreads();

    // ---- QK^T (swapped): D[kcol][q], 24 MFMA, K-frags shared across both q-subtiles
    f32x4 sa[4][2];
#pragma unroll
    for (int mt = 0; mt < 4; ++mt) { sa[mt][0] = (f32x4){0,0,0,0}; sa[mt][1] = (f32x4){0,0,0,0}; }
#pragma unroll
    for (int c = 0; c < 3; ++c)
#pragma unroll
      for (int mt = 0; mt < 4; ++mt) {
        v8bf kf = *(const v8bf*)&Kl[16 * mt + r16][c * 32 + g * 8];
        sa[mt][0] = __builtin_amdgcn_mfma_f32_16x16x32_bf16(kf, qf[0][c], sa[mt][0], 0, 0, 0);
        sa[mt][1] = __builtin_amdgcn_mfma_f32_16x16x32_bf16(kf, qf[1][c], sa[mt][1], 0, 0, 0);
      }

    // ---- bias: wave-uniform const for far tiles, per-element gather for ~7 near tiles
    const bool nearT = (kb > q0 - 162) && (kb < q0 + 226);
    float bC = 0.f;
    if (!nearT) bC = (kb < q0) ? embL[0] : embL[198];

    float pmax[2], mb[2];
#pragma unroll
    for (int sub = 0; sub < 2; ++sub) {
      float pm = -1e30f;
      int rbase = kb + 99 - qrow[sub] + 4 * g;
#pragma unroll
      for (int mt = 0; mt < 4; ++mt)
#pragma unroll
        for (int r = 0; r < 4; ++r) {
          float v = sa[mt][sub][r];
          if (nearT) {
            int idx = rbase + 16 * mt + r;
            idx = min(198, max(0, idx));
            v += embL[idx];
          }
          sa[mt][sub][r] = v;
          pm = fmaxf(pm, v);
        }
      pm = fmaxf(pm, __shfl_xor(pm, 16));
      pm = fmaxf(pm, __shfl_xor(pm, 32));
      pmax[sub] = pm;
      mb[sub] = m_run[sub] - bC;
    }

    // ---- defer-max: rescale only when running max actually grows by >8 (log2 units)
    bool ok = (pmax[0] <= mb[0] + 8.f) && (pmax[1] <= mb[1] + 8.f);
    if (!__all(ok)) {
#pragma unroll
      for (int sub = 0; sub < 2; ++sub) {
        float mn = fmaxf(m_run[sub], pmax[sub] + bC);
        float corr = exp2f(m_run[sub] - mn);
        m_run[sub] = mn;
        mb[sub] = mn - bC;
        l_run[sub] *= corr;
        float cD[4];
#pragma unroll
        for (int r = 0; r < 4; ++r) cD[r] = __shfl(corr, 4 * g + r);
#pragma unroll
        for (int nt = 0; nt < 6; ++nt)
#pragma unroll
          for (int r = 0; r < 4; ++r) acc[nt][sub][r] *= cD[r];
      }
    }

    // ---- P = exp2(lg - mb), pack to bf16 pairs, per-wave LDS
#pragma unroll
    for (int sub = 0; sub < 2; ++sub) {
      float ps = 0.f;
#pragma unroll
      for (int mt = 0; mt < 4; ++mt) {
        float p0 = exp2f(sa[mt][sub][0] - mb[sub]);
        float p1 = exp2f(sa[mt][sub][1] - mb[sub]);
        float p2 = exp2f(sa[mt][sub][2] - mb[sub]);
        float p3 = exp2f(sa[mt][sub][3] - mb[sub]);
        ps += (p0 + p1) + (p2 + p3);
        unsigned pk0, pk1;
        asm("v_cvt_pk_bf16_f32 %0, %1, %2" : "=v"(pk0) : "v"(p0), "v"(p1));
        asm("v_cvt_pk_bf16_f32 %0, %1, %2" : "=v"(pk1) : "v"(p2), "v"(p3));
        uint2 pv; pv.x = pk0; pv.y = pk1;
        *(uint2*)&Pl[wid][sub * 16 + r16][16 * mt + 4 * g] = pv;
      }
      ps += __shfl_xor(ps, 16);
      ps += __shfl_xor(ps, 32);
      l_run[sub] += ps;
    }

    // ---- PV: 24 MFMA; P frags held in regs, V^T frags shared across subs
    v8bf pf[2][2];
#pragma unroll
    for (int sub = 0; sub < 2; ++sub)
#pragma unroll
      for (int kc = 0; kc < 2; ++kc)
        pf[sub][kc] = *(const v8bf*)&Pl[wid][sub * 16 + r16][kc * 32 + g * 8];
#pragma unroll
    for (int nt = 0; nt < 6; ++nt) {
      v8bf vf0 = *(const v8bf*)&VTl[16 * nt + r16][g * 8];
      v8bf vf1 = *(const v8bf*)&VTl[16 * nt + r16][32 + g * 8];
#pragma unroll
      for (int sub = 0; sub < 2; ++sub) {
        acc[nt][sub] = __builtin_amdgcn_mfma_f32_16x16x32_bf16(pf[sub][0], vf0, acc[nt][sub], 0, 0, 0);
        acc[nt][sub] = __builtin_amdgcn_mfma_f32_16x16x32_bf16(pf[sub][1], vf1, acc[nt][sub], 0, 0, 0);
      }
    }
  }

  const int b = bh >> 3;
#pragma unroll
  for (int sub = 0; sub < 2; ++sub) {
    float lD[4];
#pragma unroll
    for (int r = 0; r < 4; ++r) lD[r] = 1.f / __shfl(l_run[sub], 4 * g + r);
#pragma unroll
    for (int nt = 0; nt < 6; ++nt) {
      int col = h * 96 + 16 * nt + r16;
#pragma unroll
      for (int r = 0; r < 4; ++r) {
        int s = q0 + wid * 32 + sub * 16 + 4 * g + r;
        ctx[((size_t)b * 2048 + s) * 768 + col] = f2b(acc[nt][sub][r] * lD[r]);
      }
    }
  }
}

// ---------------- launch ----------------
extern "C" void kernel_launch(void* const* d_in, const int* in_sizes, int n_in,
                              void* d_out, int out_size, void* d_ws, size_t ws_size,
                              hipStream_t stream) {
  const float* x = (const float*)d_in[0];
  const float* wq = (const float*)d_in[1];
  const float* wk = (const float*)d_in[2];
  const float* wv = (const float*)d_in[3];
  const float* wo = (const float*)d_in[4];
  const float* rel = (const float*)d_in[5];

  char* ws = (char*)d_ws;
  u16* xb = (u16*)(ws + 0);              // 12,582,912 B
  u16* wct = (u16*)(ws + 12582912);      //  3,538,944 B
  u16* wot = (u16*)(ws + 16121856);      //  1,179,648 B
  float* emb = (float*)(ws + 17301504);  //      6,400 B (padded)
  u16* qkv = (u16*)(ws + 17309696);      // 37,748,736 B (Q|K|V^T)
  u16* ctx = (u16*)(ws + 55058432);      // 12,582,912 B

  k_cvt_x<<<6144, 256, 0, stream>>>(x, xb, 1572864);
  k_build_wct<<<864, 256, 0, stream>>>(wq, wk, wv, wct);
  k_build_wot<<<288, 256, 0, stream>>>(wo, wot);
  k_emb<<<7, 256, 0, stream>>>(rel, emb);

  dim3 gq(18, 64);
  gemm128<0><<<gq, 256, 0, stream>>>(xb, wct, (void*)qkv);

  dim3 ga(16, 32);
  attn<<<ga, 256, 0, stream>>>(qkv, qkv + 6291456, qkv + 2 * 6291456, emb, ctx);

  dim3 go(6, 64);
  gemm128<1><<<go, 256, 0, stream>>>(ctx, wot, d_out);
}

// Round 3
// 266.602 us; speedup vs baseline: 1.4970x; 1.3789x over previous
//
#include <hip/hip_runtime.h>

typedef unsigned short u16;
typedef __bf16 v8bf __attribute__((ext_vector_type(8)));
typedef float f32x4 __attribute__((ext_vector_type(4)));
typedef float f32x16 __attribute__((ext_vector_type(16)));

#define LOG2E 1.4426950408889634f

#define GLOAD16(g, l) __builtin_amdgcn_global_load_lds( \
    (const __attribute__((address_space(1))) void*)(g), \
    (__attribute__((address_space(3))) void*)(l), 16, 0, 0)

__device__ __forceinline__ u16 f2b(float x) {
  unsigned u = __builtin_bit_cast(unsigned, x);
  unsigned r = (u + 0x7FFFu + ((u >> 16) & 1u)) >> 16;  // RNE
  return (u16)r;
}

__device__ __forceinline__ void plswap(unsigned& a, unsigned& b) {
  asm("v_permlane32_swap_b32 %0, %1" : "+v"(a), "+v"(b));
}

union V8U { uint4 u; u16 s[8]; };

// ---------------- prep kernels (outputs pre-swizzled for gload_lds GEMM) ----------------
// xb[row][cu'] : cu' = (cu&~7) | ((cu^row)&7)  (16B-unit XOR swizzle keyed on row&7)
__global__ __launch_bounds__(256) void k_cvt_x(const float* __restrict__ x, u16* __restrict__ xb, int nu) {
  int i = blockIdx.x * 256 + threadIdx.x;
  if (i >= nu) return;
  int row = i / 96, cu = i - row * 96;
  const float4* src = (const float4*)(x + (size_t)i * 8);
  float4 a = src[0], c = src[1];
  V8U o;
  o.s[0] = f2b(a.x); o.s[1] = f2b(a.y); o.s[2] = f2b(a.z); o.s[3] = f2b(a.w);
  o.s[4] = f2b(c.x); o.s[5] = f2b(c.y); o.s[6] = f2b(c.z); o.s[7] = f2b(c.w);
  int cus = (cu & ~7) | ((cu & 7) ^ (row & 7));
  *(uint4*)&xb[((size_t)row * 96 + cus) * 8] = o.u;
}

// wct[c][e] = w_m[h][e][d], c = m*768 + h*96 + d  (B^T layout, swizzled on c&7)
// W_q pre-scaled by d^-1/2 * log2(e) so logits land in log2 domain.
__global__ __launch_bounds__(256) void k_build_wct(const float* __restrict__ wq, const float* __restrict__ wk,
                                                   const float* __restrict__ wv, u16* __restrict__ wct) {
  int t = blockIdx.x * 256 + threadIdx.x;
  if (t >= 2304 * 96) return;
  int c = t / 96, e8 = t - (t / 96) * 96;
  int m = c / 768, rem = c - m * 768;
  int h = rem / 96, d = rem - (rem / 96) * 96;
  const float* src = (m == 0) ? wq : (m == 1) ? wk : wv;
  float sc = (m == 0) ? (0.10206207261596577f * LOG2E) : 1.0f;
  const float* p = src + (size_t)h * 73728 + d;
  V8U o;
  for (int i = 0; i < 8; ++i) o.s[i] = f2b(p[(size_t)(e8 * 8 + i) * 96] * sc);
  int es = (e8 & ~7) | ((e8 & 7) ^ (c & 7));
  *(uint4*)&wct[(size_t)c * 768 + es * 8] = o.u;
}

// wot[e][k] = w_o_flat[k*768 + e]  (B^T layout, swizzled on e&7)
__global__ __launch_bounds__(256) void k_build_wot(const float* __restrict__ wo, u16* __restrict__ wot) {
  int t = blockIdx.x * 256 + threadIdx.x;
  if (t >= 768 * 96) return;
  int e = t / 96, k8 = t - (t / 96) * 96;
  V8U o;
  for (int i = 0; i < 8; ++i) o.s[i] = f2b(wo[(size_t)(k8 * 8 + i) * 768 + e]);
  int ks = (k8 & ~7) | ((k8 & 7) ^ (e & 7));
  *(uint4*)&wot[(size_t)e * 768 + ks * 8] = o.u;
}

// emb[h][p] = LOG2E * sum_d rel_emb[h][p][d][0]
__global__ __launch_bounds__(256) void k_emb(const float* __restrict__ rel, float* __restrict__ emb) {
  int t = blockIdx.x * 256 + threadIdx.x;
  if (t >= 8 * 199) return;
  int h = t / 199, p = t - h * 199;
  const float4* src = (const float4*)(rel + (size_t)(h * 199 + p) * 96);
  float s = 0.f;
  for (int i = 0; i < 24; ++i) { float4 v = src[i]; s += v.x + v.y + v.z + v.w; }
  emb[h * 200 + p] = s * LOG2E;
}

// ---------------- 128x128 bf16 MFMA GEMM, K=768, gload_lds + XOR swizzle ----------------
// A, Bm stored PRE-SWIZZLED (16B units XORed on row&7) -> staging is a linear copy.
// EPI 0: Q plain [bh][s][d]; K in fragment-tile order per (bh,kb); V plain.  EPI 1: f32 C.
template <int EPI>
__global__ __launch_bounds__(256, 2) void gemm128(const u16* __restrict__ A, const u16* __restrict__ Bm,
                                                  void* __restrict__ Cout) {
  __shared__ alignas(16) u16 Abuf[2][8192];
  __shared__ alignas(16) u16 Bbuf[2][8192];
  const int tid = threadIdx.x, lane = tid & 63, wid = tid >> 6;
  const int g = lane >> 4, r16 = lane & 15;
  const int wr = wid >> 1, wc = wid & 1;
  const int Mbase = blockIdx.y * 128, Nbase = blockIdx.x * 128;
  const int srow = lane >> 3, scq = lane & 7;
  f32x4 acc[4][4];
#pragma unroll
  for (int i = 0; i < 4; ++i)
#pragma unroll
    for (int j = 0; j < 4; ++j) acc[i][j] = (f32x4){0.f, 0.f, 0.f, 0.f};

#define STAGE_G(kt, nb)                                                              \
  {                                                                                  \
    _Pragma("unroll") for (int j = 0; j < 4; ++j) {                                  \
      int blk = 4 * wid + j;                                                         \
      int row = blk * 8 + srow;                                                      \
      GLOAD16(A + (size_t)(Mbase + row) * 768 + (kt)*64 + scq * 8,                   \
              (char*)&Abuf[nb][0] + blk * 1024 + lane * 16);                         \
      GLOAD16(Bm + (size_t)(Nbase + row) * 768 + (kt)*64 + scq * 8,                  \
              (char*)&Bbuf[nb][0] + blk * 1024 + lane * 16);                         \
    }                                                                                \
  }

  STAGE_G(0, 0);
  __syncthreads();
  int cur = 0;
  const int xr = r16 & 7;
  for (int kt = 0; kt < 12; ++kt) {
    if (kt < 11) STAGE_G(kt + 1, cur ^ 1);
    __builtin_amdgcn_s_setprio(1);
#pragma unroll
    for (int ch = 0; ch < 2; ++ch) {
      v8bf af[4], bv[4];
#pragma unroll
      for (int mt = 0; mt < 4; ++mt)
        af[mt] = *(const v8bf*)&Abuf[cur][(64 * wr + 16 * mt + r16) * 64 + (((ch * 4 + g) ^ xr) * 8)];
#pragma unroll
      for (int nt = 0; nt < 4; ++nt)
        bv[nt] = *(const v8bf*)&Bbuf[cur][(64 * wc + 16 * nt + r16) * 64 + (((ch * 4 + g) ^ xr) * 8)];
#pragma unroll
      for (int mt = 0; mt < 4; ++mt)
#pragma unroll
        for (int nt = 0; nt < 4; ++nt)
          acc[mt][nt] = __builtin_amdgcn_mfma_f32_16x16x32_bf16(af[mt], bv[nt], acc[mt][nt], 0, 0, 0);
    }
    __builtin_amdgcn_s_setprio(0);
    __syncthreads();
    cur ^= 1;
  }

  if (EPI == 0) {
    u16* qkv = (u16*)Cout;
#pragma unroll
    for (int mt = 0; mt < 4; ++mt)
#pragma unroll
      for (int nt = 0; nt < 4; ++nt) {
        int col = Nbase + 64 * wc + 16 * nt + r16;
        int m = col / 768, rem = col - m * 768;
        int hh = rem / 96, d = rem - hh * 96;
#pragma unroll
        for (int r = 0; r < 4; ++r) {
          int row = Mbase + 64 * wr + 16 * mt + 4 * g + r;
          int bb = row >> 11, s = row & 2047;
          int bhv = bb * 8 + hh;
          size_t off;
          if (m == 1) {  // K fragment-tiled: unit = kblk*384 + kd*64 + hi8*32 + kl
            int kbv = s >> 6, kblk = (s >> 5) & 1, kl = s & 31;
            int kdv = d >> 4, hi8 = (d >> 3) & 1, e = d & 7;
            off = (size_t)6291456 + ((size_t)bhv * 32 + kbv) * 6144 +
                  (size_t)(kblk * 384 + kdv * 64 + hi8 * 32 + kl) * 8 + e;
          } else {
            off = (size_t)m * 6291456 + ((size_t)bhv * 2048 + s) * 96 + d;
          }
          qkv[off] = f2b(acc[mt][nt][r]);
        }
      }
  } else {
    float* C = (float*)Cout;
#pragma unroll
    for (int mt = 0; mt < 4; ++mt)
#pragma unroll
      for (int nt = 0; nt < 4; ++nt) {
        int col = Nbase + 64 * wc + 16 * nt + r16;
#pragma unroll
        for (int r = 0; r < 4; ++r) {
          int row = Mbase + 64 * wr + 16 * mt + 4 * g + r;
          C[(size_t)row * 768 + col] = acc[mt][nt][r];
        }
      }
  }
#undef STAGE_G
}

// ---------------- V -> V^T fragment-tile pack ----------------
// VT tile per (bh,kb): unit u = dt*256 + ks*64 + l holds V[k=16ks+8(l>>5)+e][d=32dt+(l&31)]
__global__ __launch_bounds__(256) void k_packV(const u16* __restrict__ v_ws, u16* __restrict__ vt) {
  __shared__ alignas(16) u16 Vl[64][104];
  int kb = blockIdx.x, bh = blockIdx.y, tid = threadIdx.x;
  const u16* src = v_ws + ((size_t)bh * 2048 + kb * 64) * 96;
#pragma unroll
  for (int j = 0; j < 3; ++j) {
    int u = tid + j * 256;
    int row = u / 12, c8 = u - (u / 12) * 12;
    *(uint4*)&Vl[row][c8 * 8] = *(const uint4*)(src + (size_t)row * 96 + c8 * 8);
  }
  __syncthreads();
  u16* dst = vt + ((size_t)bh * 32 + kb) * 6144;
#pragma unroll
  for (int j = 0; j < 3; ++j) {
    int u = tid + j * 256;
    int dt = u >> 8, ks = (u >> 6) & 3, l = u & 63;
    int dd = dt * 32 + (l & 31), kk = ks * 16 + (l >> 5) * 8;
    V8U o;
#pragma unroll
    for (int e = 0; e < 8; ++e) o.s[e] = Vl[kk + e][dd];
    *(uint4*)&dst[(size_t)u * 8] = o.u;
  }
}

// ---------------- flash attention v3: 32x32 MFMA, in-register softmax ----------------
// grid (16, 32): 128 q-rows/block, 4 waves x 32 q. KVBLK=64, 32 tiles, gload_lds double-buffer.
__global__ __launch_bounds__(256, 2) void attn(const u16* __restrict__ q_ws, const u16* __restrict__ kt_ws,
                                               const u16* __restrict__ vt_ws, const float* __restrict__ emb_ws,
                                               u16* __restrict__ ctx) {
  __shared__ alignas(16) u16 Kbuf[2][6144];
  __shared__ alignas(16) u16 Vbuf[2][6144];
  __shared__ float embL[200];
  const int tid = threadIdx.x, lane = tid & 63, wid = tid >> 6;
  const int l31 = lane & 31, hi = lane >> 5;
  const int bh = blockIdx.y, h = bh & 7, b = bh >> 3;
  const int q0 = blockIdx.x * 128;
  for (int i = tid; i < 199; i += 256) embL[i] = emb_ws[h * 200 + i];

  const int q = q0 + wid * 32 + l31;
  const u16* qp = q_ws + ((size_t)bh * 2048 + q) * 96 + hi * 8;
  v8bf qf[6];
#pragma unroll
  for (int kd = 0; kd < 6; ++kd) qf[kd] = *(const v8bf*)(qp + kd * 16);

  const u16* ktp = kt_ws + (size_t)bh * 196608;
  const u16* vtp = vt_ws + (size_t)bh * 196608;

#define STAGE_A(kv, nb)                                                         \
  {                                                                             \
    const u16* ktn = ktp + (size_t)(kv)*6144;                                   \
    const u16* vtn = vtp + (size_t)(kv)*6144;                                   \
    _Pragma("unroll") for (int j = 0; j < 3; ++j) {                             \
      int blk = wid + 4 * j;                                                    \
      GLOAD16(ktn + blk * 512 + lane * 8, (char*)&Kbuf[nb][0] + blk * 1024 + lane * 16); \
      GLOAD16(vtn + blk * 512 + lane * 8, (char*)&Vbuf[nb][0] + blk * 1024 + lane * 16); \
    }                                                                           \
  }

  STAGE_A(0, 0);
  __syncthreads();

  float m_run = -1e30f, l_run = 0.f;
  f32x16 acc[3];
  acc[0] = (f32x16)(0.f); acc[1] = (f32x16)(0.f); acc[2] = (f32x16)(0.f);
  int cur = 0;

  for (int kv = 0; kv < 32; ++kv) {
    const int kb = kv * 64;
    if (kv < 31) STAGE_A(kv + 1, cur ^ 1);
    const u16* Kc = &Kbuf[cur][0];
    const u16* Vc = &Vbuf[cur][0];

    // ---- QK^T swapped: D[kcol][q]; lane holds P[q=l31][kcol=(r&3)+8(r>>2)+4hi (+32 kblk)]
    f32x16 sa0 = (f32x16)(0.f), sa1 = (f32x16)(0.f);
    __builtin_amdgcn_s_setprio(1);
#pragma unroll
    for (int kd = 0; kd < 6; ++kd) {
      v8bf k0 = *(const v8bf*)(Kc + kd * 512 + lane * 8);
      v8bf k1 = *(const v8bf*)(Kc + 3072 + kd * 512 + lane * 8);
      sa0 = __builtin_amdgcn_mfma_f32_32x32x16_bf16(k0, qf[kd], sa0, 0, 0, 0);
      sa1 = __builtin_amdgcn_mfma_f32_32x32x16_bf16(k1, qf[kd], sa1, 0, 0, 0);
    }
    __builtin_amdgcn_s_setprio(0);

    // ---- bias: per-element gather only on near tiles; constant on far tiles
    const bool nearT = (kb > q0 - 162) && (kb < q0 + 226);
    float bC = 0.f;
    if (nearT) {
      int rb = kb + 99 - q;
#pragma unroll
      for (int r = 0; r < 16; ++r) {
        int kc = (r & 3) + 8 * (r >> 2) + 4 * hi;
        sa0[r] += embL[min(198, max(0, rb + kc))];
        sa1[r] += embL[min(198, max(0, rb + 32 + kc))];
      }
    } else {
      bC = (kb < q0) ? embL[0] : embL[198];
    }

    float pm = -1e30f;
#pragma unroll
    for (int r = 0; r < 16; ++r) pm = fmaxf(pm, fmaxf(sa0[r], sa1[r]));
    pm = fmaxf(pm, __shfl_xor(pm, 32));
    float mb = m_run - bC;

    // ---- defer-max (THR=8 in log2 units)
    if (!__all(pm <= mb + 8.f)) {
      float mn = fmaxf(m_run, pm + bC);
      float corr = exp2f(m_run - mn);
      m_run = mn;
      mb = mn - bC;
      l_run *= corr;
#pragma unroll
      for (int r = 0; r < 16; ++r) {
        float cq = __shfl(corr, (r & 3) + 8 * (r >> 2) + 4 * hi);
        acc[0][r] *= cq; acc[1][r] *= cq; acc[2][r] *= cq;
      }
    }

    // ---- P = exp2(sa - mb); pack + permlane32_swap into PV A-fragments (no LDS)
    v8bf pa[2][2];
    float ps = 0.f;
    {
      unsigned u[8];
#pragma unroll
      for (int j = 0; j < 8; ++j) {
        float p0 = exp2f(sa0[2 * j] - mb);
        float p1 = exp2f(sa0[2 * j + 1] - mb);
        ps += p0 + p1;
        asm("v_cvt_pk_bf16_f32 %0, %1, %2" : "=v"(u[j]) : "v"(p0), "v"(p1));
      }
      plswap(u[0], u[2]); plswap(u[1], u[3]); plswap(u[4], u[6]); plswap(u[5], u[7]);
      pa[0][0] = __builtin_bit_cast(v8bf, (uint4){u[0], u[1], u[2], u[3]});
      pa[0][1] = __builtin_bit_cast(v8bf, (uint4){u[4], u[5], u[6], u[7]});
    }
    {
      unsigned u[8];
#pragma unroll
      for (int j = 0; j < 8; ++j) {
        float p0 = exp2f(sa1[2 * j] - mb);
        float p1 = exp2f(sa1[2 * j + 1] - mb);
        ps += p0 + p1;
        asm("v_cvt_pk_bf16_f32 %0, %1, %2" : "=v"(u[j]) : "v"(p0), "v"(p1));
      }
      plswap(u[0], u[2]); plswap(u[1], u[3]); plswap(u[4], u[6]); plswap(u[5], u[7]);
      pa[1][0] = __builtin_bit_cast(v8bf, (uint4){u[0], u[1], u[2], u[3]});
      pa[1][1] = __builtin_bit_cast(v8bf, (uint4){u[4], u[5], u[6], u[7]});
    }
    l_run += ps;  // partial (lane half); combined at epilogue

    // ---- PV: acc[dt] += P(16k) x V^T frags
    __builtin_amdgcn_s_setprio(1);
#pragma unroll
    for (int dt = 0; dt < 3; ++dt)
#pragma unroll
      for (int ks = 0; ks < 4; ++ks) {
        v8bf vf = *(const v8bf*)(Vc + dt * 2048 + ks * 512 + lane * 8);
        acc[dt] = __builtin_amdgcn_mfma_f32_32x32x16_bf16(pa[ks >> 1][ks & 1], vf, acc[dt], 0, 0, 0);
      }
    __builtin_amdgcn_s_setprio(0);

    __syncthreads();
    cur ^= 1;
  }
#undef STAGE_A

  // ---- epilogue: normalize, write ctx pre-swizzled (on s&7) for the out-GEMM
  float lf = l_run + __shfl_xor(l_run, 32);
#pragma unroll
  for (int r = 0; r < 16; ++r) {
    int qr = (r & 3) + 8 * (r >> 2) + 4 * hi;
    float inv = 1.f / __shfl(lf, qr);
    int s = q0 + wid * 32 + qr;
#pragma unroll
    for (int dt = 0; dt < 3; ++dt) {
      int col = h * 96 + dt * 32 + l31;
      int cu = col >> 3;
      int cus = (cu & ~7) | ((cu & 7) ^ (s & 7));
      ctx[((size_t)b * 2048 + s) * 768 + cus * 8 + (col & 7)] = f2b(acc[dt][r] * inv);
    }
  }
}

// ---------------- launch ----------------
extern "C" void kernel_launch(void* const* d_in, const int* in_sizes, int n_in,
                              void* d_out, int out_size, void* d_ws, size_t ws_size,
                              hipStream_t stream) {
  const float* x = (const float*)d_in[0];
  const float* wq = (const float*)d_in[1];
  const float* wk = (const float*)d_in[2];
  const float* wv = (const float*)d_in[3];
  const float* wo = (const float*)d_in[4];
  const float* rel = (const float*)d_in[5];

  char* ws = (char*)d_ws;
  u16* xb = (u16*)(ws + 0);              // 12,582,912 B (xb; reused as VT after gemm<0>)
  u16* wct = (u16*)(ws + 12582912);      //  3,538,944 B
  u16* wot = (u16*)(ws + 16121856);      //  1,179,648 B
  float* emb = (float*)(ws + 17301504);  //      6,400 B (padded)
  u16* qkv = (u16*)(ws + 17309696);      // 37,748,736 B (Q | K-tiled | V)
  u16* ctx = (u16*)(ws + 55058432);      // 12,582,912 B

  k_cvt_x<<<3072, 256, 0, stream>>>(x, xb, 786432);
  k_build_wct<<<864, 256, 0, stream>>>(wq, wk, wv, wct);
  k_build_wot<<<288, 256, 0, stream>>>(wo, wot);
  k_emb<<<7, 256, 0, stream>>>(rel, emb);

  dim3 gq(18, 64);
  gemm128<0><<<gq, 256, 0, stream>>>(xb, wct, (void*)qkv);

  u16* vt = xb;  // xb dead after gemm<0>
  dim3 gp(32, 32);
  k_packV<<<gp, 256, 0, stream>>>(qkv + 2 * 6291456, vt);

  dim3 ga(16, 32);
  attn<<<ga, 256, 0, stream>>>(qkv, qkv + 6291456, vt, emb, ctx);

  dim3 go(6, 64);
  gemm128<1><<<go, 256, 0, stream>>>(ctx, wot, d_out);
}

// Round 5
// 249.452 us; speedup vs baseline: 1.5999x; 1.0688x over previous
//
#include <hip/hip_runtime.h>

typedef unsigned short u16;
typedef __bf16 v8bf __attribute__((ext_vector_type(8)));
typedef float f32x4 __attribute__((ext_vector_type(4)));
typedef float f32x16 __attribute__((ext_vector_type(16)));

#define LOG2E 1.4426950408889634f

#define GLOAD16(g, l) __builtin_amdgcn_global_load_lds( \
    (const __attribute__((address_space(1))) void*)(g), \
    (__attribute__((address_space(3))) void*)(l), 16, 0, 0)

__device__ __forceinline__ u16 f2b(float x) {
  unsigned u = __builtin_bit_cast(unsigned, x);
  unsigned r = (u + 0x7FFFu + ((u >> 16) & 1u)) >> 16;  // RNE
  return (u16)r;
}

__device__ __forceinline__ void plswap(unsigned& a, unsigned& b) {
  asm("v_permlane32_swap_b32 %0, %1" : "+v"(a), "+v"(b));
}

union V8U { uint4 u; u16 s[8]; };

// ---------------- fused prep kernel ----------------
// blocks [0,3072): x -> bf16 pre-swizzled; [3072,3936): wct; [3936,4224): wot; [4224,4231): emb
__global__ __launch_bounds__(256) void k_prep(const float* __restrict__ x, const float* __restrict__ wq,
                                              const float* __restrict__ wk, const float* __restrict__ wv,
                                              const float* __restrict__ wo, const float* __restrict__ rel,
                                              u16* __restrict__ xb, u16* __restrict__ wct,
                                              u16* __restrict__ wot, float* __restrict__ emb) {
  int bx = blockIdx.x;
  if (bx < 3072) {
    int i = bx * 256 + threadIdx.x;  // 786432 units exactly
    int row = i / 96, cu = i - row * 96;
    const float4* src = (const float4*)(x + (size_t)i * 8);
    float4 a = src[0], c = src[1];
    V8U o;
    o.s[0] = f2b(a.x); o.s[1] = f2b(a.y); o.s[2] = f2b(a.z); o.s[3] = f2b(a.w);
    o.s[4] = f2b(c.x); o.s[5] = f2b(c.y); o.s[6] = f2b(c.z); o.s[7] = f2b(c.w);
    int cus = (cu & ~7) | ((cu & 7) ^ (row & 7));
    *(uint4*)&xb[((size_t)row * 96 + cus) * 8] = o.u;
  } else if (bx < 3936) {
    int t = (bx - 3072) * 256 + threadIdx.x;  // 221184 exactly
    int c = t / 96, e8 = t - (t / 96) * 96;
    int m = c / 768, rem = c - m * 768;
    int h = rem / 96, d = rem - (rem / 96) * 96;
    const float* src = (m == 0) ? wq : (m == 1) ? wk : wv;
    float sc = (m == 0) ? (0.10206207261596577f * LOG2E) : 1.0f;
    const float* p = src + (size_t)h * 73728 + d;
    V8U o;
    for (int i = 0; i < 8; ++i) o.s[i] = f2b(p[(size_t)(e8 * 8 + i) * 96] * sc);
    int es = (e8 & ~7) | ((e8 & 7) ^ (c & 7));
    *(uint4*)&wct[(size_t)c * 768 + es * 8] = o.u;
  } else if (bx < 4224) {
    int t = (bx - 3936) * 256 + threadIdx.x;  // 73728 exactly
    int e = t / 96, k8 = t - (t / 96) * 96;
    V8U o;
    for (int i = 0; i < 8; ++i) o.s[i] = f2b(wo[(size_t)(k8 * 8 + i) * 768 + e]);
    int ks = (k8 & ~7) | ((k8 & 7) ^ (e & 7));
    *(uint4*)&wot[(size_t)e * 768 + ks * 8] = o.u;
  } else {
    int t = (bx - 4224) * 256 + threadIdx.x;
    if (t < 8 * 199) {
      int h = t / 199, p = t - h * 199;
      const float4* src = (const float4*)(rel + (size_t)(h * 199 + p) * 96);
      float s = 0.f;
      for (int i = 0; i < 24; ++i) { float4 v = src[i]; s += v.x + v.y + v.z + v.w; }
      emb[h * 200 + p] = s * LOG2E;
    }
  }
}

// ---------------- 128x128 bf16 MFMA GEMM, K=768, gload_lds + XOR swizzle ----------------
// A, Bm PRE-SWIZZLED (16B units XORed on row&7). LDS-repack epilogues:
// EPI 0: Q plain [bh][s][d]; K fragment-tiled; V^T fragment-tiled.  EPI 1: f32 C, float4 stores.
template <int EPI>
__global__ __launch_bounds__(256, 2) void gemm128(const u16* __restrict__ A, const u16* __restrict__ Bm,
                                                  void* __restrict__ Cout) {
  __shared__ alignas(16) char smem[65536];
  const int tid = threadIdx.x, lane = tid & 63, wid = tid >> 6;
  const int g = lane >> 4, r16 = lane & 15;
  const int wr = wid >> 1, wc = wid & 1;
  const int Mbase = blockIdx.y * 128, Nbase = blockIdx.x * 128;
  const int srow = lane >> 3, scq = lane & 7;
  f32x4 acc[4][4];
#pragma unroll
  for (int i = 0; i < 4; ++i)
#pragma unroll
    for (int j = 0; j < 4; ++j) acc[i][j] = (f32x4){0.f, 0.f, 0.f, 0.f};

#define STAGE_G(kt, nb)                                                              \
  {                                                                                  \
    _Pragma("unroll") for (int j = 0; j < 4; ++j) {                                  \
      int blk = 4 * wid + j;                                                         \
      int row = blk * 8 + srow;                                                      \
      GLOAD16(A + (size_t)(Mbase + row) * 768 + (kt)*64 + scq * 8,                   \
              smem + (nb)*16384 + blk * 1024 + lane * 16);                           \
      GLOAD16(Bm + (size_t)(Nbase + row) * 768 + (kt)*64 + scq * 8,                  \
              smem + 32768 + (nb)*16384 + blk * 1024 + lane * 16);                   \
    }                                                                                \
  }

  STAGE_G(0, 0);
  __syncthreads();
  int cur = 0;
  const int xr = r16 & 7;
  for (int kt = 0; kt < 12; ++kt) {
    if (kt < 11) STAGE_G(kt + 1, cur ^ 1);
    __builtin_amdgcn_s_setprio(1);
#pragma unroll
    for (int ch = 0; ch < 2; ++ch) {
      v8bf af[4], bv[4];
#pragma unroll
      for (int mt = 0; mt < 4; ++mt)
        af[mt] = *(const v8bf*)((u16*)smem + cur * 8192 + (64 * wr + 16 * mt + r16) * 64 + ((ch * 4 + g) ^ xr) * 8);
#pragma unroll
      for (int nt = 0; nt < 4; ++nt)
        bv[nt] = *(const v8bf*)((u16*)(smem + 32768) + cur * 8192 + (64 * wc + 16 * nt + r16) * 64 + ((ch * 4 + g) ^ xr) * 8);
#pragma unroll
      for (int mt = 0; mt < 4; ++mt)
#pragma unroll
        for (int nt = 0; nt < 4; ++nt)
          acc[mt][nt] = __builtin_amdgcn_mfma_f32_16x16x32_bf16(af[mt], bv[nt], acc[mt][nt], 0, 0, 0);
    }
    __builtin_amdgcn_s_setprio(0);
    __syncthreads();
    cur ^= 1;
  }
#undef STAGE_G

  const int colbase = Nbase + 64 * wc;
  const int sb = Mbase + 64 * wr;
  const int bI = sb >> 11, sgb = sb & 2047;

  if (EPI == 0) {
    u16* qkv = (u16*)Cout;
    const int m = colbase / 768;
    u16* W = (u16*)smem + wid * 4608;  // [64][72] u16 per wave
    if (m == 2) {  // store transposed: W[col][row]
#pragma unroll
      for (int mt = 0; mt < 4; ++mt)
#pragma unroll
        for (int nt = 0; nt < 4; ++nt) {
          int c = 16 * nt + r16;
#pragma unroll
          for (int r = 0; r < 4; ++r) W[c * 72 + 16 * mt + 4 * g + r] = f2b(acc[mt][nt][r]);
        }
    } else {  // W[row][col]
#pragma unroll
      for (int mt = 0; mt < 4; ++mt)
#pragma unroll
        for (int nt = 0; nt < 4; ++nt) {
          int c = 16 * nt + r16;
#pragma unroll
          for (int r = 0; r < 4; ++r) W[(16 * mt + 4 * g + r) * 72 + c] = f2b(acc[mt][nt][r]);
        }
    }
    __builtin_amdgcn_sched_barrier(0);
    if (m == 0) {
#pragma unroll
      for (int j = 0; j < 8; ++j) {
        int s_l = (lane >> 3) + 8 * j, dchunk = lane & 7;
        int col = colbase + dchunk * 8;
        int hh = col / 96, dd = col - hh * 96;
        size_t off = ((size_t)(bI * 8 + hh) * 2048 + sgb + s_l) * 96 + dd;
        *(uint4*)&qkv[off] = *(const uint4*)&W[s_l * 72 + dchunk * 8];
      }
    } else if (m == 1) {
      u16* kt_out = qkv + 6291456;
      const int kbv = sgb >> 6;
#pragma unroll
      for (int j = 0; j < 8; ++j) {
        int kl = lane & 31, hi8 = lane >> 5;
        int row_l = (j >> 2) * 32 + kl;
        int d_l = (j & 3) * 16 + hi8 * 8;
        int rem = colbase + d_l - 768;
        int hh = rem / 96, dd = rem - hh * 96;
        size_t off = (((size_t)(bI * 8 + hh) * 32 + kbv) * 768 +
                      (j >> 2) * 384 + (dd >> 4) * 64 + ((dd >> 3) & 1) * 32 + kl) * 8;
        *(uint4*)&kt_out[off] = *(const uint4*)&W[row_l * 72 + d_l];
      }
    } else {
      u16* vt_out = qkv + 2 * 6291456;
      const int kbv = sgb >> 6;
#pragma unroll
      for (int j = 0; j < 8; ++j) {
        int seg = j & 1, ks = j >> 1;
        int d_l = seg * 32 + (lane & 31);
        int k_l = ks * 16 + (lane >> 5) * 8;
        int rem = colbase + d_l - 1536;
        int hh = rem / 96, dd = rem - hh * 96;
        size_t off = (((size_t)(bI * 8 + hh) * 32 + kbv) * 768 + (dd >> 5) * 256 + ks * 64 + lane) * 8;
        *(uint4*)&vt_out[off] = *(const uint4*)&W[d_l * 72 + k_l];
      }
    }
  } else {
    float* C = (float*)Cout;
    float* Wf = (float*)smem + wid * 4096;  // [64][64] f32 per wave
#pragma unroll
    for (int mt = 0; mt < 4; ++mt)
#pragma unroll
      for (int nt = 0; nt < 4; ++nt) {
        int c = 16 * nt + r16;
#pragma unroll
        for (int r = 0; r < 4; ++r) Wf[(16 * mt + 4 * g + r) * 64 + c] = acc[mt][nt][r];
      }
    __builtin_amdgcn_sched_barrier(0);
#pragma unroll
    for (int j = 0; j < 16; ++j) {
      int s_l = (lane >> 4) + 4 * j, echunk = lane & 15;
      int row = sb + s_l;
      *(float4*)&C[(size_t)row * 768 + colbase + echunk * 4] = *(const float4*)&Wf[s_l * 64 + echunk * 4];
    }
  }
}

// ---------------- flash attention v4: counted-vmcnt barriers, triple-buffer ----------------
// grid (16, 32): 128 q-rows/block, 4 waves x 32 q. KVBLK=64, 32 tiles.
__global__ __launch_bounds__(256, 2) void attn(const u16* __restrict__ q_ws, const u16* __restrict__ kt_ws,
                                               const u16* __restrict__ vt_ws, const float* __restrict__ emb_ws,
                                               u16* __restrict__ ctx) {
  __shared__ alignas(16) u16 Kbuf[3][6144];
  __shared__ alignas(16) u16 Vbuf[3][6144];
  __shared__ float embL[200];
  const int tid = threadIdx.x, lane = tid & 63, wid = tid >> 6;
  const int l31 = lane & 31, hi = lane >> 5;
  const int bh = blockIdx.y, h = bh & 7, b = bh >> 3;
  const int q0 = blockIdx.x * 128;
  for (int i = tid; i < 199; i += 256) embL[i] = emb_ws[h * 200 + i];

  const int q = q0 + wid * 32 + l31;
  const u16* qp = q_ws + ((size_t)bh * 2048 + q) * 96 + hi * 8;
  v8bf qf[6];
#pragma unroll
  for (int kd = 0; kd < 6; ++kd) qf[kd] = *(const v8bf*)(qp + kd * 16);

  const u16* ktp = kt_ws + (size_t)bh * 196608;
  const u16* vtp = vt_ws + (size_t)bh * 196608;

#define STAGE_A(kv, nb)                                                                    \
  {                                                                                        \
    const u16* ktn = ktp + (size_t)(kv)*6144;                                              \
    const u16* vtn = vtp + (size_t)(kv)*6144;                                              \
    _Pragma("unroll") for (int j = 0; j < 3; ++j) {                                        \
      int blk = wid + 4 * j;                                                               \
      GLOAD16(ktn + blk * 512 + lane * 8, (char*)&Kbuf[nb][0] + blk * 1024 + lane * 16);   \
      GLOAD16(vtn + blk * 512 + lane * 8, (char*)&Vbuf[nb][0] + blk * 1024 + lane * 16);   \
    }                                                                                      \
  }

  STAGE_A(0, 0);
  STAGE_A(1, 1);
  __syncthreads();  // one-time full drain (covers embL too)

  float m_run = -1e30f, l_run = 0.f;
  f32x16 acc[3];
  acc[0] = (f32x16)(0.f); acc[1] = (f32x16)(0.f); acc[2] = (f32x16)(0.f);
  int cur = 0;

  for (int kv = 0; kv < 32; ++kv) {
    const int kb = kv * 64;
    if (kv < 30) {
      int nb = cur + 2; if (nb >= 3) nb -= 3;
      STAGE_A(kv + 2, nb);
    }
    const u16* Kc = &Kbuf[cur][0];
    const u16* Vc = &Vbuf[cur][0];

    // ---- QK^T swapped: lane holds P[q=l31][kcol=(r&3)+8(r>>2)+4hi (+32 kblk)]
    f32x16 sa0 = (f32x16)(0.f), sa1 = (f32x16)(0.f);
    __builtin_amdgcn_s_setprio(1);
#pragma unroll
    for (int kd = 0; kd < 6; ++kd) {
      v8bf k0 = *(const v8bf*)(Kc + kd * 512 + lane * 8);
      v8bf k1 = *(const v8bf*)(Kc + 3072 + kd * 512 + lane * 8);
      sa0 = __builtin_amdgcn_mfma_f32_32x32x16_bf16(k0, qf[kd], sa0, 0, 0, 0);
      sa1 = __builtin_amdgcn_mfma_f32_32x32x16_bf16(k1, qf[kd], sa1, 0, 0, 0);
    }
    __builtin_amdgcn_s_setprio(0);

    // ---- bias: gather on near tiles only
    const bool nearT = (kb > q0 - 162) && (kb < q0 + 226);
    float bC = 0.f;
    if (nearT) {
      int rb = kb + 99 - q;
#pragma unroll
      for (int r = 0; r < 16; ++r) {
        int kc = (r & 3) + 8 * (r >> 2) + 4 * hi;
        sa0[r] += embL[min(198, max(0, rb + kc))];
        sa1[r] += embL[min(198, max(0, rb + 32 + kc))];
      }
    } else {
      bC = (kb < q0) ? embL[0] : embL[198];
    }

    float pm = -1e30f;
#pragma unroll
    for (int r = 0; r < 16; ++r) pm = fmaxf(pm, fmaxf(sa0[r], sa1[r]));
    pm = fmaxf(pm, __shfl_xor(pm, 32));
    float mb = m_run - bC;

    // ---- defer-max (THR=8 log2 units)
    if (!__all(pm <= mb + 8.f)) {
      float mn = fmaxf(m_run, pm + bC);
      float corr = exp2f(m_run - mn);
      m_run = mn;
      mb = mn - bC;
      l_run *= corr;
#pragma unroll
      for (int r = 0; r < 16; ++r) {
        float cq = __shfl(corr, (r & 3) + 8 * (r >> 2) + 4 * hi);
        acc[0][r] *= cq; acc[1][r] *= cq; acc[2][r] *= cq;
      }
    }

    // ---- P = exp2(sa - mb); cvt_pk + permlane32_swap -> PV A-fragments (no LDS)
    v8bf pa[2][2];
    float ps = 0.f;
    {
      unsigned u[8];
#pragma unroll
      for (int j = 0; j < 8; ++j) {
        float p0 = exp2f(sa0[2 * j] - mb);
        float p1 = exp2f(sa0[2 * j + 1] - mb);
        ps += p0 + p1;
        asm("v_cvt_pk_bf16_f32 %0, %1, %2" : "=v"(u[j]) : "v"(p0), "v"(p1));
      }
      plswap(u[0], u[2]); plswap(u[1], u[3]); plswap(u[4], u[6]); plswap(u[5], u[7]);
      pa[0][0] = __builtin_bit_cast(v8bf, (uint4){u[0], u[1], u[2], u[3]});
      pa[0][1] = __builtin_bit_cast(v8bf, (uint4){u[4], u[5], u[6], u[7]});
    }
    {
      unsigned u[8];
#pragma unroll
      for (int j = 0; j < 8; ++j) {
        float p0 = exp2f(sa1[2 * j] - mb);
        float p1 = exp2f(sa1[2 * j + 1] - mb);
        ps += p0 + p1;
        asm("v_cvt_pk_bf16_f32 %0, %1, %2" : "=v"(u[j]) : "v"(p0), "v"(p1));
      }
      plswap(u[0], u[2]); plswap(u[1], u[3]); plswap(u[4], u[6]); plswap(u[5], u[7]);
      pa[1][0] = __builtin_bit_cast(v8bf, (uint4){u[0], u[1], u[2], u[3]});
      pa[1][1] = __builtin_bit_cast(v8bf, (uint4){u[4], u[5], u[6], u[7]});
    }
    l_run += ps;  // lane-half partial; combined at epilogue

    // ---- PV
    __builtin_amdgcn_s_setprio(1);
#pragma unroll
    for (int dt = 0; dt < 3; ++dt)
#pragma unroll
      for (int ks = 0; ks < 4; ++ks) {
        v8bf vf = *(const v8bf*)(Vc + dt * 2048 + ks * 512 + lane * 8);
        acc[dt] = __builtin_amdgcn_mfma_f32_32x32x16_bf16(pa[ks >> 1][ks & 1], vf, acc[dt], 0, 0, 0);
      }
    __builtin_amdgcn_s_setprio(0);

    // ---- counted-vmcnt barrier (T4): keep next-next stage in flight, never drain to 0
    if (kv < 30) {
      asm volatile("s_waitcnt vmcnt(6)" ::: "memory");
      __builtin_amdgcn_s_barrier();
      __builtin_amdgcn_sched_barrier(0);
    } else if (kv == 30) {
      asm volatile("s_waitcnt vmcnt(0)" ::: "memory");
      __builtin_amdgcn_s_barrier();
      __builtin_amdgcn_sched_barrier(0);
    }
    cur = (cur == 2) ? 0 : cur + 1;
  }
#undef STAGE_A

  // ---- epilogue: normalize, write ctx pre-swizzled (on s&7) for the out-GEMM
  float lf = l_run + __shfl_xor(l_run, 32);
#pragma unroll
  for (int r = 0; r < 16; ++r) {
    int qr = (r & 3) + 8 * (r >> 2) + 4 * hi;
    float inv = 1.f / __shfl(lf, qr);
    int s = q0 + wid * 32 + qr;
#pragma unroll
    for (int dt = 0; dt < 3; ++dt) {
      int col = h * 96 + dt * 32 + l31;
      int cu = col >> 3;
      int cus = (cu & ~7) | ((cu & 7) ^ (s & 7));
      ctx[((size_t)b * 2048 + s) * 768 + cus * 8 + (col & 7)] = f2b(acc[dt][r] * inv);
    }
  }
}

// ---------------- launch ----------------
extern "C" void kernel_launch(void* const* d_in, const int* in_sizes, int n_in,
                              void* d_out, int out_size, void* d_ws, size_t ws_size,
                              hipStream_t stream) {
  const float* x = (const float*)d_in[0];
  const float* wq = (const float*)d_in[1];
  const float* wk = (const float*)d_in[2];
  const float* wv = (const float*)d_in[3];
  const float* wo = (const float*)d_in[4];
  const float* rel = (const float*)d_in[5];

  char* ws = (char*)d_ws;
  u16* xb = (u16*)(ws + 0);              // 12,582,912 B
  u16* wct = (u16*)(ws + 12582912);      //  3,538,944 B
  u16* wot = (u16*)(ws + 16121856);      //  1,179,648 B
  float* emb = (float*)(ws + 17301504);  //      8,192 B (padded)
  u16* qkv = (u16*)(ws + 17309696);      // 37,748,736 B (Q | K-tiled | V^T-tiled)
  u16* ctx = (u16*)(ws + 55058432);      // 12,582,912 B

  k_prep<<<4231, 256, 0, stream>>>(x, wq, wk, wv, wo, rel, xb, wct, wot, emb);

  dim3 gq(18, 64);
  gemm128<0><<<gq, 256, 0, stream>>>(xb, wct, (void*)qkv);

  dim3 ga(16, 32);
  attn<<<ga, 256, 0, stream>>>(qkv, qkv + 6291456, qkv + 2 * 6291456, emb, ctx);

  dim3 go(6, 64);
  gemm128<1><<<go, 256, 0, stream>>>(ctx, wot, d_out);
}